// Round 8
// baseline (488.680 us; speedup 1.0000x reference)
//
#include <hip/hip_runtime.h>

// SoftCLDiceLoss fully fused, round 10: register-resident dilate, 1 barrier/iter.
// Evidence R2/R4/R6/R7: dur pinned 411-418 us while occupancy (44-87%), VALU
// work (+/-15%), conflicts (5.6-9.5e7) all swung -> LDS pipe is the saturated
// resource (~0.8e6 of 1.0e6 cycles: ~136k b128 wave-ops/CU + 372k conflict
// cycles). Fix: strip s erodes rows 11+4s..16+4s IN REGISTERS (2-row overlap
// with neighbor strip = duplicate VALU, which is slack), dilates from regs
// (zero LDS ops in phase B -> 1 barrier/iter), keeps prev-iter erode interior
// ep[4] in regs for the delta. Outer shrinking band rows ([k+1,10]u[77,86-k])
// done as single-row erodes by strips 0..9-k. LDS traffic -39%, barriers -50%,
// VALU +10%. 256 threads, launch_bounds(256,3) (VGPR cap 85, peak ~76 live),
// 4 blocks/CU (36.6 KB LDS). Complement skel update c'=c*(1-d).

#define TILE 64
#define HALO 12
#define RROWS 88
#define SD 52                    // row stride in dwords
#define IMG 1024
#define NBC 16
#define NITER 11
#define LEPS 1e-6f

typedef unsigned int u32;
typedef _Float16 hv2 __attribute__((ext_vector_type(2)));

struct __align__(16) U4 { u32 v[4]; };

__device__ __forceinline__ hv2 H2(u32 x) { union { u32 u; hv2 h; } c; c.u = x; return c.h; }
__device__ __forceinline__ u32 U2(hv2 x) { union { u32 u; hv2 h; } c; c.h = x; return c.u; }
__device__ __forceinline__ hv2 hmin2v(hv2 a, hv2 b) { return __builtin_elementwise_min(a, b); }
__device__ __forceinline__ hv2 hmax2v(hv2 a, hv2 b) { return __builtin_elementwise_max(a, b); }
__device__ __forceinline__ u32 dpp_prev16(u32 x) {   // lane i <- i-1 within 16-lane row, 0-fill
    return (u32)__builtin_amdgcn_update_dpp(0, (int)x, 0x101, 0xf, 0xf, true);
}
__device__ __forceinline__ u32 dpp_next16(u32 x) {   // lane i <- i+1 within 16-lane row, 0-fill
    return (u32)__builtin_amdgcn_update_dpp(0, (int)x, 0x111, 0xf, 0xf, true);
}
__device__ __forceinline__ u32 alignh(u32 hi, u32 lo) {   // (lo.hi16, hi.lo16) packed
    return (u32)((((unsigned long long)hi << 32) | lo) >> 16);
}
__device__ __forceinline__ float sigmoidf(float x) { return 1.0f / (1.0f + __expf(-x)); }

// 3-wide horizontal min/max over 8 packed halves; neighbors via DPP.
template<bool IS_MIN>
__device__ __forceinline__ void hpass(const u32 d[4], u32 o[4]) {
    u32 dm = dpp_prev16(d[3]);
    u32 dp = dpp_next16(d[0]);
    u32 a[5];
    a[0] = alignh(d[0], dm);
    a[1] = alignh(d[1], d[0]);
    a[2] = alignh(d[2], d[1]);
    a[3] = alignh(d[3], d[2]);
    a[4] = alignh(dp,   d[3]);
#pragma unroll
    for (int q = 0; q < 4; ++q) {
        if (IS_MIN) o[q] = U2(hmin2v(hmin2v(H2(a[q]), H2(d[q])), H2(a[q + 1])));
        else        o[q] = U2(hmax2v(hmax2v(H2(a[q]), H2(d[q])), H2(a[q + 1])));
    }
}

// single-row erode: cur row r -> oth row r (vertical min then hpass)
__device__ __forceinline__ void erode_row(const u32* cur, u32* oth, int r,
                                          int coldw, bool wact) {
    U4 a, b, c, vv, o;
    *(uint4*)a.v = *(const uint4*)(cur + (r - 1) * SD + coldw);
    *(uint4*)b.v = *(const uint4*)(cur + r * SD + coldw);
    *(uint4*)c.v = *(const uint4*)(cur + (r + 1) * SD + coldw);
#pragma unroll
    for (int q = 0; q < 4; ++q)
        vv.v[q] = U2(hmin2v(hmin2v(H2(a.v[q]), H2(b.v[q])), H2(c.v[q])));
    hpass<true>(vv.v, o.v);
    if (wact) *(uint4*)(oth + r * SD + coldw) = *(const uint4*)o.v;
}

__global__ __launch_bounds__(256, 3)
void skel_tile_kernel(const float* __restrict__ pred,
                      const float* __restrict__ target,
                      float* __restrict__ ws)
{
    __shared__ __align__(16) u32 bufA[RROWS * SD];
    __shared__ __align__(16) u32 bufB[RROWS * SD];

    const int tid = threadIdx.x;
    const int bc  = blockIdx.z & (NBC - 1);
    const int img = blockIdx.z >> 4;
    const int r0  = blockIdx.y * TILE;
    const int c0  = blockIdx.x * TILE;

    const float* src = (img == 0) ? pred : target;
    const size_t base = (size_t)bc * (size_t)(IMG * IMG);

    const bool edgeT = (blockIdx.y == 0);
    const bool edgeB = (blockIdx.y == 15);
    const bool edgeL = (blockIdx.x == 0);
    const bool edgeR = (blockIdx.x == 15);

    // ---- load region rows 0..87, cols 0..95 (halves), replicate-clamped ----
    for (int t = tid; t < 88 * 12; t += 256) {
        int rr = t / 12;
        int g  = t - rr * 12;
        int gr = min(max(r0 + rr - HALO, 0), IMG - 1);
        const float* rowp = src + base + (size_t)gr * IMG;
        float f[8];
        int gc0 = c0 + 8 * g - HALO;
        if (g <= 10 && gc0 >= 0 && gc0 + 8 <= IMG) {
            float4 v0 = *(const float4*)(rowp + gc0);
            float4 v1 = *(const float4*)(rowp + gc0 + 4);
            f[0] = v0.x; f[1] = v0.y; f[2] = v0.z; f[3] = v0.w;
            f[4] = v1.x; f[5] = v1.y; f[6] = v1.z; f[7] = v1.w;
        } else {
#pragma unroll
            for (int i = 0; i < 8; ++i) {
                int rc = min(8 * g + i, 87);                    // region col clamp (pad cols)
                int gc = min(max(c0 + rc - HALO, 0), IMG - 1);  // image col clamp
                f[i] = rowp[gc];
            }
        }
        U4 u;
#pragma unroll
        for (int q = 0; q < 4; ++q) {
            float a = f[2 * q], b = f[2 * q + 1];
            if (img == 0) { a = sigmoidf(a); b = sigmoidf(b); }
            else { a = fminf(fmaxf(a, 0.f), 1.f); b = fminf(fmaxf(b, 0.f), 1.f); }
            hv2 p; p[0] = (_Float16)a; p[1] = (_Float16)b;
            u.v[q] = U2(p);
        }
        *(uint4*)&bufA[rr * SD + 4 * g] = *(const uint4*)u.v;
    }

    // ---- strip / lane geometry: 16 strips of 16 lanes ----
    const int strip = tid >> 4;                 // 0..15
    const int g16   = tid & 15;                 // lane within DPP row
    const int coldw = 4 * min(g16, 11);         // clamped dword col (16B aligned)
    const bool wact = (g16 < 12);

    const int rs_d = 12 + 4 * strip;            // dilate out rows rs_d..rs_d+3
    const int re0  = 11 + 4 * strip;            // erode-in-reg rows re0..re0+5

    hv2 Cv[4][4];                               // complement: c = 1 - skel
#pragma unroll
    for (int j = 0; j < 4; ++j)
#pragma unroll
        for (int q = 0; q < 4; ++q) { Cv[j][q][0] = (_Float16)1; Cv[j][q][1] = (_Float16)1; }

    u32* cur = bufA;
    u32* oth = bufB;

    __syncthreads();

    // ---- prologue: delta rows of iter 0 = original input rows rs_d..rs_d+3 ----
    U4 ep[4];
#pragma unroll
    for (int i = 0; i < 4; ++i)
        *(uint4*)ep[i].v = *(const uint4*)(cur + (rs_d + i) * SD + coldw);

#pragma unroll 1
    for (int k = 0; k < NITER; ++k) {
        // ===== Phase A: erode (reads cur, writes oth), dilate inputs -> regs =====
        U4 e[6];
        {
            const u32* p = cur + (re0 - 1) * SD + coldw;
            U4 r0v, r1v, r2v;
            *(uint4*)r0v.v = *(const uint4*)(p);
            *(uint4*)r1v.v = *(const uint4*)(p + SD);
#pragma unroll
            for (int j = 0; j < 6; ++j) {
                *(uint4*)r2v.v = *(const uint4*)(p + (j + 2) * SD);
                U4 vv;
#pragma unroll
                for (int q = 0; q < 4; ++q)
                    vv.v[q] = U2(hmin2v(hmin2v(H2(r0v.v[q]), H2(r1v.v[q])), H2(r2v.v[q])));
                hpass<true>(vv.v, e[j].v);
                r0v = r1v; r1v = r2v;
            }
            // write band rows 11..76: strip s writes e[0..3] (rows 11+4s..14+4s),
            // strip 15 also e[4],e[5] (rows 75,76)
            u32* qo = oth + re0 * SD + coldw;
            if (wact) {
#pragma unroll
                for (int j = 0; j < 4; ++j)
                    *(uint4*)(qo + j * SD) = *(const uint4*)e[j].v;
                if (strip == 15) {
                    *(uint4*)(qo + 4 * SD) = *(const uint4*)e[4].v;
                    *(uint4*)(qo + 5 * SD) = *(const uint4*)e[5].v;
                }
            }
        }
        // shrinking outer band: rows [k+1,10] and [77,86-k], one strip each
        {
            const int nx = 10 - k;               // 10..0
            if (strip < nx) {
                erode_row(cur, oth, (k + 1) + strip, coldw, wact);   // top
                erode_row(cur, oth, (86 - k) - strip, coldw, wact);  // bottom
            }
        }
        __syncthreads();

        // ===== Phase B: dilate + delta + skel update — registers only =====
        {
            U4 elo = e[0], ehi = e[5];
            if (edgeT && strip == 0)  elo = e[1];   // global row -1 pad (replicate==inf-pad here)
            if (edgeB && strip == 15) ehi = e[4];   // global row IMG pad
            U4 V[4], m[4];
#pragma unroll
            for (int q = 0; q < 4; ++q) {
                V[0].v[q] = U2(hmax2v(hmax2v(H2(elo.v[q]),  H2(e[1].v[q])), H2(e[2].v[q])));
                V[1].v[q] = U2(hmax2v(hmax2v(H2(e[1].v[q]), H2(e[2].v[q])), H2(e[3].v[q])));
                V[2].v[q] = U2(hmax2v(hmax2v(H2(e[2].v[q]), H2(e[3].v[q])), H2(e[4].v[q])));
                V[3].v[q] = U2(hmax2v(hmax2v(H2(e[3].v[q]), H2(e[4].v[q])), H2(ehi.v[q])));
            }
#pragma unroll
            for (int i = 0; i < 4; ++i) hpass<false>(V[i].v, m[i].v);

            // image-edge column repair (replicate); commutes with vertical max
            if (edgeL && g16 == 1) {
#pragma unroll
                for (int i = 0; i < 4; ++i) {   // out col12 lo := max(x12,x13)
                    u32 d2 = V[i].v[2];
                    u32 sw = (d2 >> 16) | (d2 << 16);
                    u32 pm = U2(hmax2v(H2(d2), H2(sw)));
                    m[i].v[2] = (m[i].v[2] & 0xFFFF0000u) | (pm & 0xFFFFu);
                }
            }
            if (edgeR && g16 == 9) {
#pragma unroll
                for (int i = 0; i < 4; ++i) {   // out col75 hi := max(x74,x75)
                    u32 d1 = V[i].v[1];
                    u32 sw = (d1 >> 16) | (d1 << 16);
                    u32 pm = U2(hmax2v(H2(d1), H2(sw)));
                    m[i].v[1] = (m[i].v[1] & 0x0000FFFFu) | (pm & 0xFFFF0000u);
                }
            }

#pragma unroll
            for (int i = 0; i < 4; ++i) {
#pragma unroll
                for (int qd = 0; qd < 4; ++qd) {
                    hv2 D = H2(m[i].v[qd]);               // dilate-out (3x3 done)
                    hv2 z; z[0] = (_Float16)0; z[1] = (_Float16)0;
                    hv2 d = hmax2v(H2(ep[i].v[qd]) - D, z);   // d in [0,1]
                    hv2 c = Cv[i][qd];
                    Cv[i][qd] = c - c * d;                // c' = c*(1-d)  (pk_fma)
                }
                ep[i] = e[i + 1];                         // next delta rows rs_d..rs_d+3
            }
        }

        { u32* t_ = cur; cur = oth; oth = t_; }
    }

    // ---- tile sums: sum(skel), sum(skel * other), skel = 1 - c ----
    const float* osrc = (img == 0) ? target : pred;
    float s_sum = 0.0f, sp_sum = 0.0f;
#pragma unroll
    for (int j = 0; j < 4; ++j) {
        int orow = r0 + 4 * strip + j;
#pragma unroll
        for (int q = 0; q < 4; ++q) {
#pragma unroll
            for (int e2 = 0; e2 < 2; ++e2) {
                int rc = 8 * g16 + 2 * q + e2;
                if (rc >= 12 && rc <= 75) {
                    float sv = 1.0f - (float)Cv[j][q][e2];
                    float ov = osrc[base + (size_t)orow * IMG + (c0 + rc - HALO)];
                    if (img == 1) ov = sigmoidf(ov);
                    s_sum  += sv;
                    sp_sum += sv * ov;
                }
            }
        }
    }

#pragma unroll
    for (int off = 32; off > 0; off >>= 1) {
        s_sum  += __shfl_down(s_sum,  off, 64);
        sp_sum += __shfl_down(sp_sum, off, 64);
    }
    float* red = (float*)bufA;
    if ((tid & 63) == 0) {
        red[(tid >> 6) * 2 + 0] = sp_sum;
        red[(tid >> 6) * 2 + 1] = s_sum;
    }
    __syncthreads();
    if (tid == 0) {
        float a = (red[0] + red[2]) + (red[4] + red[6]);
        float b = (red[1] + red[3]) + (red[5] + red[7]);
        float* acc = ws + (size_t)blockIdx.z * 2;
        atomicAdd(acc + 0, a);   // sum skel * other
        atomicAdd(acc + 1, b);   // sum skel
    }
}

__global__ void finalize_kernel(const float* __restrict__ ws, float* __restrict__ out)
{
    if (threadIdx.x == 0) {
        float acc = 0.0f;
        for (int bc = 0; bc < NBC; ++bc) {
            float spt = ws[(0 * NBC + bc) * 2 + 0];
            float sp  = ws[(0 * NBC + bc) * 2 + 1];
            float stp = ws[(1 * NBC + bc) * 2 + 0];
            float st  = ws[(1 * NBC + bc) * 2 + 1];
            float tprec = spt / (sp + LEPS);
            float tsens = stp / (st + LEPS);
            acc += 1.0f - 2.0f * tprec * tsens / (tprec + tsens + LEPS);
        }
        out[0] = acc / (float)NBC;
    }
}

extern "C" void kernel_launch(void* const* d_in, const int* in_sizes, int n_in,
                              void* d_out, int out_size, void* d_ws, size_t ws_size,
                              hipStream_t stream) {
    const float* pred   = (const float*)d_in[0];
    const float* target = (const float*)d_in[1];
    float* ws  = (float*)d_ws;
    float* out = (float*)d_out;

    hipMemsetAsync(d_ws, 0, 2 * NBC * 2 * sizeof(float), stream);

    dim3 grid(IMG / TILE, IMG / TILE, 2 * NBC);   // 16 x 16 x 32
    skel_tile_kernel<<<grid, 256, 0, stream>>>(pred, target, ws);
    finalize_kernel<<<1, 64, 0, stream>>>(ws, out);
}